// Round 7
// baseline (262.500 us; speedup 1.0000x reference)
//
#include <hip/hip_runtime.h>
#include <hip/hip_bf16.h>

#define B_  4
#define N_  2048
#define E_  256
#define H_  8
#define D_  32
#define QT  16
#define KC  64
#define VTP 72   // V^T row stride (ushorts): 144B, 16B-aligned
#define PP  72   // P row stride (ushorts)
#define LOG2E 1.4426950408889634f

typedef __attribute__((ext_vector_type(8))) short bfx8;
typedef __attribute__((ext_vector_type(4))) float fx4;

__device__ __forceinline__ unsigned short f2bf(float f) {
    unsigned int u = __float_as_uint(f);
    u += 0x7fffu + ((u >> 16) & 1u);   // round-to-nearest-even
    return (unsigned short)(u >> 16);
}

// ---------- prep: Wt[n][k] = bf16(W[k][n]) for 6 weight matrices ----------
__global__ __launch_bounds__(256) void prep_w(
    const float* Wa, const float* Wb, const float* Wc,
    const float* Wd, const float* We, const float* Wf,
    unsigned short* Oa, unsigned short* Ob, unsigned short* Oc,
    unsigned short* Od, unsigned short* Oe, unsigned short* Of)
{
    int z = blockIdx.z;
    const float* src = z == 0 ? Wa : z == 1 ? Wb : z == 2 ? Wc
                     : z == 3 ? Wd : z == 4 ? We : Wf;
    unsigned short* dst = z == 0 ? Oa : z == 1 ? Ob : z == 2 ? Oc
                        : z == 3 ? Od : z == 4 ? Oe : Of;
    __shared__ float t[32][33];
    int n0 = blockIdx.x * 32, k0 = blockIdx.y * 32;
    int tx = threadIdx.x & 31, ty = threadIdx.x >> 5;
#pragma unroll
    for (int i = 0; i < 4; i++)
        t[ty + i * 8][tx] = src[(k0 + ty + i * 8) * E_ + n0 + tx];
    __syncthreads();
#pragma unroll
    for (int i = 0; i < 4; i++)
        dst[(n0 + ty + i * 8) * E_ + k0 + tx] = f2bf(t[tx][ty + i * 8]);
}

// ---------- LayerNorm: one block (256 thr) per row; bf16 out ----------
__global__ __launch_bounds__(256) void ln_kernel(const float* __restrict__ x,
                                                 const float* __restrict__ g,
                                                 const float* __restrict__ be,
                                                 unsigned short* __restrict__ out)
{
    long row = blockIdx.x;
    int t = threadIdx.x;
    float v = x[row * E_ + t];
    float s = v, s2 = v * v;
#pragma unroll
    for (int off = 32; off; off >>= 1) {
        s  += __shfl_xor(s,  off, 64);
        s2 += __shfl_xor(s2, off, 64);
    }
    __shared__ float rs[4], rs2[4];
    int w = t >> 6;
    if ((t & 63) == 0) { rs[w] = s; rs2[w] = s2; }
    __syncthreads();
    s  = rs[0] + rs[1] + rs[2] + rs[3];
    s2 = rs2[0] + rs2[1] + rs2[2] + rs2[3];
    float mu  = s * (1.0f / E_);
    float var = s2 * (1.0f / E_) - mu * mu;
    float rstd = rsqrtf(var + 1e-5f);
    out[row * E_ + t] = f2bf((v - mu) * rstd * g[t] + be[t]);
}

// ---------- bf16 MFMA GEMM core (64x64 tile, K=256 strip in LDS) ----------
__device__ __forceinline__ void gemm_core(
    const unsigned short* __restrict__ A,
    const unsigned short* __restrict__ Wt,
    const float* __restrict__ bias,
    const float* __restrict__ resid,
    void* __restrict__ Cv, int relu, int obf, int m0, int n0)
{
    __shared__ unsigned short As[64 * 264];
    __shared__ unsigned short Bs[64 * 264];
    int tid = threadIdx.x;

    {   // stage both 64x256 strips (contiguous rows), coalesced 16B/lane
        const unsigned short* Ab = A  + (long)m0 * E_;
        const unsigned short* Bb = Wt + (long)n0 * E_;
        bfx8 va[8], vb[8];
#pragma unroll
        for (int i = 0; i < 8; i++) va[i] = *(const bfx8*)&Ab[(i * 256 + tid) * 8];
#pragma unroll
        for (int i = 0; i < 8; i++) vb[i] = *(const bfx8*)&Bb[(i * 256 + tid) * 8];
#pragma unroll
        for (int i = 0; i < 8; i++) {
            int fo = i * 256 + tid;
            int row = fo >> 5, c8 = fo & 31;
            *(bfx8*)&As[row * 264 + c8 * 8] = va[i];
            *(bfx8*)&Bs[row * 264 + c8 * 8] = vb[i];
        }
    }
    __syncthreads();

    int lane = tid & 63, w = tid >> 6;
    int c = lane & 15, g = lane >> 4;
    int wm = (w >> 1) * 32, wn = (w & 1) * 32;
    fx4 acc[2][2] = {};

#pragma unroll
    for (int ks = 0; ks < 8; ks++) {
        bfx8 a0 = *(const bfx8*)&As[(wm + c)      * 264 + ks * 32 + g * 8];
        bfx8 a1 = *(const bfx8*)&As[(wm + 16 + c) * 264 + ks * 32 + g * 8];
        bfx8 b0 = *(const bfx8*)&Bs[(wn + c)      * 264 + ks * 32 + g * 8];
        bfx8 b1 = *(const bfx8*)&Bs[(wn + 16 + c) * 264 + ks * 32 + g * 8];
        acc[0][0] = __builtin_amdgcn_mfma_f32_16x16x32_bf16(a0, b0, acc[0][0], 0, 0, 0);
        acc[0][1] = __builtin_amdgcn_mfma_f32_16x16x32_bf16(a0, b1, acc[0][1], 0, 0, 0);
        acc[1][0] = __builtin_amdgcn_mfma_f32_16x16x32_bf16(a1, b0, acc[1][0], 0, 0, 0);
        acc[1][1] = __builtin_amdgcn_mfma_f32_16x16x32_bf16(a1, b1, acc[1][1], 0, 0, 0);
    }

#pragma unroll
    for (int fm = 0; fm < 2; fm++)
#pragma unroll
        for (int r = 0; r < 4; r++) {
            int m = m0 + wm + fm * 16 + g * 4 + r;
#pragma unroll
            for (int fn = 0; fn < 2; fn++) {
                int n = n0 + wn + fn * 16 + c;
                float o = acc[fm][fn][r];
                if (bias)  o += bias[n];
                if (relu)  o = fmaxf(o, 0.f);
                if (resid) o += resid[(long)m * E_ + n];
                if (obf) ((unsigned short*)Cv)[(long)m * E_ + n] = f2bf(o);
                else     ((float*)Cv)[(long)m * E_ + n] = o;
            }
        }
}

__global__ __launch_bounds__(256, 2) void gemm_mfma(
    const unsigned short* __restrict__ A,
    const unsigned short* __restrict__ Wt,
    const float* __restrict__ bias,
    const float* __restrict__ resid,
    void* __restrict__ Cv, int relu, int obf)
{
    gemm_core(A, Wt, bias, resid, Cv, relu, obf, blockIdx.x * 64, blockIdx.y * 64);
}

// merged QKV: blockIdx.z selects weight/output
__global__ __launch_bounds__(256, 2) void gemm_qkv(
    const unsigned short* __restrict__ A,
    const unsigned short* __restrict__ Wq, unsigned short* __restrict__ qo,
    const unsigned short* __restrict__ Wk, unsigned short* __restrict__ ko,
    const unsigned short* __restrict__ Wv, unsigned short* __restrict__ vo)
{
    int z = blockIdx.z;
    const unsigned short* Wt = z == 0 ? Wq : z == 1 ? Wk : Wv;
    unsigned short*       Cv = z == 0 ? qo : z == 1 ? ko : vo;
    gemm_core(A, Wt, nullptr, nullptr, Cv, 0, 1, blockIdx.x * 64, blockIdx.y * 64);
}

// ---------- barrier-free MFMA flash attention, fixed-max softmax --------------
// Pipeline discipline (vmcnt-aware):
//   per body: issue V(i+1) FIRST, then K(i+1), then infl(i+2) — so the V-pack
//   (first consumer) waits vmcnt(8), keeping K+infl in flight across bodies.
//   infl is 2 chunks deep (only HBM-cold stream, ~900cyc).
// XCD swizzle: blocks on one XCD share the same batch b -> K/V (2MB) stay
// L2-resident despite the 67MB influence stream.
__global__ __launch_bounds__(512, 4) void attn_mfma(
    const unsigned short* __restrict__ q,
    const unsigned short* __restrict__ k,
    const unsigned short* __restrict__ v,
    const float* __restrict__ infl,
    const float* __restrict__ iw1p, const float* __restrict__ ib1p,
    const float* __restrict__ iw2p, const float* __restrict__ ib2p,
    unsigned short* __restrict__ out)
{
    // XCD-aware: xcd = bx&7 (round-robin dispatch); same-b blocks share an XCD
    const int bx  = blockIdx.x;
    const int xcd = bx & 7;
    const int b   = xcd >> 1;
    const int q0  = (((xcd & 1) << 6) | (bx >> 3)) * QT;
    const int tid = threadIdx.x;
    const int h    = tid >> 6;      // wave id = head
    const int lane = tid & 63;
    const int c = lane & 15, g = lane >> 4;
    const int g4 = g * 4;

    const float iw1e = iw1p[0] * LOG2E, ib1e = ib1p[0] * LOG2E;
    const float iw2 = iw2p[0], ib2 = ib2p[0];
    const float scale2 = 0.17677669529663687f * LOG2E;  // log2e/sqrt(32)
    const float cadd = ib1e - 16.0f * LOG2E;            // ib1*log2e - M2

    __shared__ unsigned short vt_lds[H_][D_][VTP];      // wave-private slices
    __shared__ unsigned short p_lds[H_][QT][PP];        // wave-private slices

    // Q fragment: lane holds Q[q0+c][h*32 + g*8 .. +7]
    bfx8 qf = *(const bfx8*)&q[((long)(b * N_ + q0 + c)) * E_ + h * D_ + g * 8];

    const float* fbase = &infl[((long)(b * N_ + q0 + c)) * N_];
    const unsigned short* kbase = &k[((long)(b * N_) + c) * E_ + h * D_ + g * 8];
    const int p2 = lane & 31, dh = (lane >> 5) * 16;
    const unsigned short* vbase = &v[((long)(b * N_) + 2 * p2) * E_ + h * D_ + dh];
    unsigned int* vtw = (unsigned int*)&vt_lds[h][0][0];

    fx4 o0 = {0.f, 0.f, 0.f, 0.f};
    fx4 o1 = {0.f, 0.f, 0.f, 0.f};
    float l_acc = 0.f;
    const fx4 zero = {0.f, 0.f, 0.f, 0.f};

    // ---- prologue ----
    // infl 2-deep: fi(0) and fi(KC)
    float4 fA0 = *(const float4*)&fbase[ 0 + g4];
    float4 fA1 = *(const float4*)&fbase[16 + g4];
    float4 fA2 = *(const float4*)&fbase[32 + g4];
    float4 fA3 = *(const float4*)&fbase[48 + g4];
    float4 fB0 = *(const float4*)&fbase[KC +  0 + g4];
    float4 fB1 = *(const float4*)&fbase[KC + 16 + g4];
    float4 fB2 = *(const float4*)&fbase[KC + 32 + g4];
    float4 fB3 = *(const float4*)&fbase[KC + 48 + g4];
    // K(0)
    bfx8 ck0 = *(const bfx8*)(kbase +  0L * E_);
    bfx8 ck1 = *(const bfx8*)(kbase + 16L * E_);
    bfx8 ck2 = *(const bfx8*)(kbase + 32L * E_);
    bfx8 ck3 = *(const bfx8*)(kbase + 48L * E_);
    {   // V(0): load + pack into LDS
        bfx8 va0 = *(const bfx8*)(vbase);
        bfx8 va1 = *(const bfx8*)(vbase + 8);
        bfx8 vb0 = *(const bfx8*)(vbase + E_);
        bfx8 vb1 = *(const bfx8*)(vbase + E_ + 8);
#pragma unroll
        for (int i = 0; i < 8; i++) {
            unsigned int val = (unsigned int)(unsigned short)va0[i] |
                               ((unsigned int)(unsigned short)vb0[i] << 16);
            vtw[(dh + i) * (VTP / 2) + p2] = val;
        }
#pragma unroll
        for (int i = 0; i < 8; i++) {
            unsigned int val = (unsigned int)(unsigned short)va1[i] |
                               ((unsigned int)(unsigned short)vb1[i] << 16);
            vtw[(dh + 8 + i) * (VTP / 2) + p2] = val;
        }
    }

    for (int kk = 0; kk < N_; kk += KC) {
        const int kp1 = (kk +     KC) & (N_ - 1);   // next chunk (wraps; discarded)
        const int kp2 = (kk + 2 * KC) & (N_ - 1);   // chunk after next

        // ---- issue order matters: V (consumed first, this body's bottom) ...
        const unsigned short* nvs = vbase + (long)kp1 * E_;
        bfx8 nva0 = *(const bfx8*)(nvs);
        bfx8 nva1 = *(const bfx8*)(nvs + 8);
        bfx8 nvb0 = *(const bfx8*)(nvs + E_);
        bfx8 nvb1 = *(const bfx8*)(nvs + E_ + 8);
        // ... then K (consumed top of next body) ...
        bfx8 nk0 = *(const bfx8*)(kbase + (long)(kp1 +  0) * E_);
        bfx8 nk1 = *(const bfx8*)(kbase + (long)(kp1 + 16) * E_);
        bfx8 nk2 = *(const bfx8*)(kbase + (long)(kp1 + 32) * E_);
        bfx8 nk3 = *(const bfx8*)(kbase + (long)(kp1 + 48) * E_);
        // ... then infl, 2 chunks ahead (consumed 2 bodies later)
        float4 fC0 = *(const float4*)&fbase[kp2 +  0 + g4];
        float4 fC1 = *(const float4*)&fbase[kp2 + 16 + g4];
        float4 fC2 = *(const float4*)&fbase[kp2 + 32 + g4];
        float4 fC3 = *(const float4*)&fbase[kp2 + 48 + g4];

        // ---- QK^T on current K (loaded one body ago)
        fx4 st0, st1, st2, st3;
        __builtin_amdgcn_s_setprio(1);
        st0 = __builtin_amdgcn_mfma_f32_16x16x32_bf16(ck0, qf, zero, 0, 0, 0);
        st1 = __builtin_amdgcn_mfma_f32_16x16x32_bf16(ck1, qf, zero, 0, 0, 0);
        st2 = __builtin_amdgcn_mfma_f32_16x16x32_bf16(ck2, qf, zero, 0, 0, 0);
        st3 = __builtin_amdgcn_mfma_f32_16x16x32_bf16(ck3, qf, zero, 0, 0, 0);
        __builtin_amdgcn_s_setprio(0);

        // ---- fixed-max softmax on fi loaded TWO bodies ago
#pragma unroll
        for (int t = 0; t < 4; t++) {
            fx4 stv = (t == 0) ? st0 : (t == 1) ? st1 : (t == 2) ? st2 : st3;
            float4 ft = (t == 0) ? fA0 : (t == 1) ? fA1 : (t == 2) ? fA2 : fA3;
            float fr[4] = {ft.x, ft.y, ft.z, ft.w};
            float pr[4];
#pragma unroll
            for (int r = 0; r < 4; r++) {
                float s = fmaf(stv[r], scale2, fmaf(fr[r], iw1e, cadd));
                float p = __builtin_amdgcn_exp2f(s);
                l_acc += p;
                pr[r] = p * fmaf(iw2, fr[r], ib2);
            }
            unsigned int lo = (unsigned int)f2bf(pr[0]) | ((unsigned int)f2bf(pr[1]) << 16);
            unsigned int hi = (unsigned int)f2bf(pr[2]) | ((unsigned int)f2bf(pr[3]) << 16);
            unsigned long long pw = (unsigned long long)lo | ((unsigned long long)hi << 32);
            *(unsigned long long*)&p_lds[h][c][t * 16 + g4] = pw;
        }

        // ---- PV on V^T packed at the END of the previous body
        __builtin_amdgcn_s_setprio(1);
#pragma unroll
        for (int kh = 0; kh < 2; kh++) {
            bfx8 pf  = *(const bfx8*)&p_lds[h][c][g * 8 + kh * 32];
            bfx8 vf0 = *(const bfx8*)&vt_lds[h][c][g * 8 + kh * 32];
            bfx8 vf1 = *(const bfx8*)&vt_lds[h][16 + c][g * 8 + kh * 32];
            o0 = __builtin_amdgcn_mfma_f32_16x16x32_bf16(pf, vf0, o0, 0, 0, 0);
            o1 = __builtin_amdgcn_mfma_f32_16x16x32_bf16(pf, vf1, o1, 0, 0, 0);
        }
        __builtin_amdgcn_s_setprio(0);

        // ---- pack next V (first-issued this body -> waits vmcnt(8), K+infl fly)
#pragma unroll
        for (int i = 0; i < 8; i++) {
            unsigned int val = (unsigned int)(unsigned short)nva0[i] |
                               ((unsigned int)(unsigned short)nvb0[i] << 16);
            vtw[(dh + i) * (VTP / 2) + p2] = val;
        }
#pragma unroll
        for (int i = 0; i < 8; i++) {
            unsigned int val = (unsigned int)(unsigned short)nva1[i] |
                               ((unsigned int)(unsigned short)nvb1[i] << 16);
            vtw[(dh + 8 + i) * (VTP / 2) + p2] = val;
        }

        // ---- rotate pipeline registers
        ck0 = nk0; ck1 = nk1; ck2 = nk2; ck3 = nk3;
        fA0 = fB0; fA1 = fB1; fA2 = fB2; fA3 = fB3;
        fB0 = fC0; fB1 = fC1; fB2 = fC2; fB3 = fC3;
    }

    // epilogue: l reduce over groups (lane owns q=c), transpose to o-layout
    float l_red = l_acc;
    l_red += __shfl_xor(l_red, 16);
    l_red += __shfl_xor(l_red, 32);
#pragma unroll
    for (int r = 0; r < 4; r++) {
        float l_q = __shfl(l_red, (lane & 48) | (g4 + r), 64);
        float inv = 1.0f / l_q;
        long rowbase = ((long)(b * N_ + q0 + g4 + r)) * E_ + h * D_;
        out[rowbase + c]      = f2bf(o0[r] * inv);
        out[rowbase + 16 + c] = f2bf(o1[r] * inv);
    }
}

// ------------------------------- launch ---------------------------------------
extern "C" void kernel_launch(void* const* d_in, const int* in_sizes, int n_in,
                              void* d_out, int out_size, void* d_ws, size_t ws_size,
                              hipStream_t stream)
{
    (void)in_sizes; (void)n_in; (void)out_size; (void)ws_size;
    const float* x    = (const float*)d_in[0];
    const float* infl = (const float*)d_in[1];
    const float* Wq   = (const float*)d_in[2];
    const float* Wk   = (const float*)d_in[3];
    const float* Wv   = (const float*)d_in[4];
    const float* Wo   = (const float*)d_in[5];
    const float* bo   = (const float*)d_in[6];
    const float* iw1  = (const float*)d_in[7];
    const float* ib1  = (const float*)d_in[8];
    const float* iw2  = (const float*)d_in[9];
    const float* ib2  = (const float*)d_in[10];
    const float* W1   = (const float*)d_in[11];
    const float* b1   = (const float*)d_in[12];
    const float* W2   = (const float*)d_in[13];
    const float* b2   = (const float*)d_in[14];
    const float* g1   = (const float*)d_in[15];
    const float* be1  = (const float*)d_in[16];
    const float* g2   = (const float*)d_in[17];
    const float* be2  = (const float*)d_in[18];

    char* base = (char*)d_ws;
    float*          hb  = (float*)base;                                   // 8 MB
    unsigned short* lnb = (unsigned short*)(base + (8  << 20));           // 4 MB
    unsigned short* qb  = (unsigned short*)(base + (12 << 20));           // 4 MB
    unsigned short* kb  = (unsigned short*)(base + (16 << 20));           // 4 MB
    unsigned short* vb  = (unsigned short*)(base + (20 << 20));           // 4 MB
    unsigned short* wqt = (unsigned short*)(base + (24 << 20));           // 6x128KB
    unsigned short* wkt = wqt + 65536;
    unsigned short* wvt = wkt + 65536;
    unsigned short* wot = wvt + 65536;
    unsigned short* w1t = wot + 65536;
    unsigned short* w2t = w1t + 65536;

    dim3 gemm_grid(128, 4);

    prep_w<<<dim3(8, 8, 6), 256, 0, stream>>>(Wq, Wk, Wv, Wo, W1, W2,
                                              wqt, wkt, wvt, wot, w1t, w2t);
    // 1. ln1 = LN(x) -> bf16
    ln_kernel<<<B_ * N_, 256, 0, stream>>>(x, g1, be1, lnb);
    // 2. q,k,v in ONE launch (z selects weight/output)
    gemm_qkv<<<dim3(128, 4, 3), 256, 0, stream>>>(lnb, wqt, qb, wkt, kb, wvt, vb);
    // 3. attention (bf16 out into lnb)
    attn_mfma<<<B_ * (N_ / QT), 512, 0, stream>>>(qb, kb, vb, infl,
                                                  iw1, ib1, iw2, ib2, lnb);
    // 4. h = attn @ Wo + bo + x (fp32)
    gemm_mfma<<<gemm_grid, 256, 0, stream>>>(lnb, wot, bo, x, hb, 0, 0);
    // 5. ln2 = LN(h) -> bf16
    ln_kernel<<<B_ * N_, 256, 0, stream>>>(hb, g2, be2, lnb);
    // 6. t = relu(ln2 @ W1 + b1) -> bf16 (reuse qb)
    gemm_mfma<<<gemm_grid, 256, 0, stream>>>(lnb, w1t, b1, nullptr, qb, 1, 1);
    // 7. out = t @ W2 + b2 + h (fp32)
    gemm_mfma<<<gemm_grid, 256, 0, stream>>>(qb, w2t, b2, hb, (float*)d_out, 0, 0);
}

// Round 8
// 198.487 us; speedup vs baseline: 1.3225x; 1.3225x over previous
//
#include <hip/hip_runtime.h>
#include <hip/hip_bf16.h>

#define B_  4
#define N_  2048
#define E_  256
#define H_  8
#define D_  32
#define QT  32   // q-rows per block
#define KC  64   // keys per chunk
#define VTP 72   // V^T row stride (ushorts): 144B, 16B-aligned
#define PP  72   // P row stride (ushorts)
#define IFP 68   // infl row stride (ushorts): 136B, 8B-aligned
#define LOG2E 1.4426950408889634f

typedef __attribute__((ext_vector_type(8))) short bfx8;
typedef __attribute__((ext_vector_type(4))) float fx4;

__device__ __forceinline__ unsigned short f2bf(float f) {
    unsigned int u = __float_as_uint(f);
    u += 0x7fffu + ((u >> 16) & 1u);   // round-to-nearest-even
    return (unsigned short)(u >> 16);
}

// ---------- prep: Wt[n][k] = bf16(W[k][n]) for 6 weight matrices ----------
__global__ __launch_bounds__(256) void prep_w(
    const float* Wa, const float* Wb, const float* Wc,
    const float* Wd, const float* We, const float* Wf,
    unsigned short* Oa, unsigned short* Ob, unsigned short* Oc,
    unsigned short* Od, unsigned short* Oe, unsigned short* Of)
{
    int z = blockIdx.z;
    const float* src = z == 0 ? Wa : z == 1 ? Wb : z == 2 ? Wc
                     : z == 3 ? Wd : z == 4 ? We : Wf;
    unsigned short* dst = z == 0 ? Oa : z == 1 ? Ob : z == 2 ? Oc
                        : z == 3 ? Od : z == 4 ? Oe : Of;
    __shared__ float t[32][33];
    int n0 = blockIdx.x * 32, k0 = blockIdx.y * 32;
    int tx = threadIdx.x & 31, ty = threadIdx.x >> 5;
#pragma unroll
    for (int i = 0; i < 4; i++)
        t[ty + i * 8][tx] = src[(k0 + ty + i * 8) * E_ + n0 + tx];
    __syncthreads();
#pragma unroll
    for (int i = 0; i < 4; i++)
        dst[(n0 + ty + i * 8) * E_ + k0 + tx] = f2bf(t[tx][ty + i * 8]);
}

// ---------- LayerNorm: one block (256 thr) per row; bf16 out ----------
__global__ __launch_bounds__(256) void ln_kernel(const float* __restrict__ x,
                                                 const float* __restrict__ g,
                                                 const float* __restrict__ be,
                                                 unsigned short* __restrict__ out)
{
    long row = blockIdx.x;
    int t = threadIdx.x;
    float v = x[row * E_ + t];
    float s = v, s2 = v * v;
#pragma unroll
    for (int off = 32; off; off >>= 1) {
        s  += __shfl_xor(s,  off, 64);
        s2 += __shfl_xor(s2, off, 64);
    }
    __shared__ float rs[4], rs2[4];
    int w = t >> 6;
    if ((t & 63) == 0) { rs[w] = s; rs2[w] = s2; }
    __syncthreads();
    s  = rs[0] + rs[1] + rs[2] + rs[3];
    s2 = rs2[0] + rs2[1] + rs2[2] + rs2[3];
    float mu  = s * (1.0f / E_);
    float var = s2 * (1.0f / E_) - mu * mu;
    float rstd = rsqrtf(var + 1e-5f);
    out[row * E_ + t] = f2bf((v - mu) * rstd * g[t] + be[t]);
}

// ---------- bf16 MFMA GEMM core (64x64 tile, K=256 strip in LDS) ----------
__device__ __forceinline__ void gemm_core(
    const unsigned short* __restrict__ A,
    const unsigned short* __restrict__ Wt,
    const float* __restrict__ bias,
    const float* __restrict__ resid,
    void* __restrict__ Cv, int relu, int obf, int m0, int n0)
{
    __shared__ unsigned short As[64 * 264];
    __shared__ unsigned short Bs[64 * 264];
    int tid = threadIdx.x;

    {   // stage both 64x256 strips (contiguous rows), coalesced 16B/lane
        const unsigned short* Ab = A  + (long)m0 * E_;
        const unsigned short* Bb = Wt + (long)n0 * E_;
        bfx8 va[8], vb[8];
#pragma unroll
        for (int i = 0; i < 8; i++) va[i] = *(const bfx8*)&Ab[(i * 256 + tid) * 8];
#pragma unroll
        for (int i = 0; i < 8; i++) vb[i] = *(const bfx8*)&Bb[(i * 256 + tid) * 8];
#pragma unroll
        for (int i = 0; i < 8; i++) {
            int fo = i * 256 + tid;
            int row = fo >> 5, c8 = fo & 31;
            *(bfx8*)&As[row * 264 + c8 * 8] = va[i];
            *(bfx8*)&Bs[row * 264 + c8 * 8] = vb[i];
        }
    }
    __syncthreads();

    int lane = tid & 63, w = tid >> 6;
    int c = lane & 15, g = lane >> 4;
    int wm = (w >> 1) * 32, wn = (w & 1) * 32;
    fx4 acc[2][2] = {};

#pragma unroll
    for (int ks = 0; ks < 8; ks++) {
        bfx8 a0 = *(const bfx8*)&As[(wm + c)      * 264 + ks * 32 + g * 8];
        bfx8 a1 = *(const bfx8*)&As[(wm + 16 + c) * 264 + ks * 32 + g * 8];
        bfx8 b0 = *(const bfx8*)&Bs[(wn + c)      * 264 + ks * 32 + g * 8];
        bfx8 b1 = *(const bfx8*)&Bs[(wn + 16 + c) * 264 + ks * 32 + g * 8];
        acc[0][0] = __builtin_amdgcn_mfma_f32_16x16x32_bf16(a0, b0, acc[0][0], 0, 0, 0);
        acc[0][1] = __builtin_amdgcn_mfma_f32_16x16x32_bf16(a0, b1, acc[0][1], 0, 0, 0);
        acc[1][0] = __builtin_amdgcn_mfma_f32_16x16x32_bf16(a1, b0, acc[1][0], 0, 0, 0);
        acc[1][1] = __builtin_amdgcn_mfma_f32_16x16x32_bf16(a1, b1, acc[1][1], 0, 0, 0);
    }

#pragma unroll
    for (int fm = 0; fm < 2; fm++)
#pragma unroll
        for (int r = 0; r < 4; r++) {
            int m = m0 + wm + fm * 16 + g * 4 + r;
#pragma unroll
            for (int fn = 0; fn < 2; fn++) {
                int n = n0 + wn + fn * 16 + c;
                float o = acc[fm][fn][r];
                if (bias)  o += bias[n];
                if (relu)  o = fmaxf(o, 0.f);
                if (resid) o += resid[(long)m * E_ + n];
                if (obf) ((unsigned short*)Cv)[(long)m * E_ + n] = f2bf(o);
                else     ((float*)Cv)[(long)m * E_ + n] = o;
            }
        }
}

__global__ __launch_bounds__(256, 2) void gemm_mfma(
    const unsigned short* __restrict__ A,
    const unsigned short* __restrict__ Wt,
    const float* __restrict__ bias,
    const float* __restrict__ resid,
    void* __restrict__ Cv, int relu, int obf)
{
    gemm_core(A, Wt, bias, resid, Cv, relu, obf, blockIdx.x * 64, blockIdx.y * 64);
}

// merged QKV: blockIdx.z selects weight/output
__global__ __launch_bounds__(256, 2) void gemm_qkv(
    const unsigned short* __restrict__ A,
    const unsigned short* __restrict__ Wq, unsigned short* __restrict__ qo,
    const unsigned short* __restrict__ Wk, unsigned short* __restrict__ ko,
    const unsigned short* __restrict__ Wv, unsigned short* __restrict__ vo)
{
    int z = blockIdx.z;
    const unsigned short* Wt = z == 0 ? Wq : z == 1 ? Wk : Wv;
    unsigned short*       Cv = z == 0 ? qo : z == 1 ? ko : vo;
    gemm_core(A, Wt, nullptr, nullptr, Cv, 0, 1, blockIdx.x * 64, blockIdx.y * 64);
}

// ---------- MFMA flash attention, QT=32, cooperative infl, barrier-pinned -----
// fixed-max softmax: p' = exp2(s*log2e - M2); out = (sum p'*rw*v)/(sum p').
// Body kk: [issue K/V(kk+1), infl(kk+2)] -> softmax(kk)+PV(kk) -> bar ->
//          ds_write infl(kk+1) (old regs) -> bar -> QK(kk+1)+Vpack(kk+1).
// All vmcnt waits land on loads issued a full body (~500cyc) earlier; barriers
// prevent the compiler sinking prefetches to their uses.
__global__ __launch_bounds__(512, 4) void attn_mfma(
    const unsigned short* __restrict__ q,
    const unsigned short* __restrict__ k,
    const unsigned short* __restrict__ v,
    const float* __restrict__ infl,
    const float* __restrict__ iw1p, const float* __restrict__ ib1p,
    const float* __restrict__ iw2p, const float* __restrict__ ib2p,
    unsigned short* __restrict__ out)
{
    // XCD clustering: same batch b on same XCD (bx&7 round-robin dispatch)
    const int bx  = blockIdx.x;                 // 256 blocks
    const int xcd = bx & 7;
    const int b   = xcd >> 1;
    const int q0  = ((bx >> 3) + ((xcd & 1) << 5)) * QT;
    const int tid = threadIdx.x;
    const int h    = tid >> 6;      // wave id = head
    const int lane = tid & 63;
    const int c = lane & 15, g = lane >> 4, g4 = g * 4;

    const float iw1e = iw1p[0] * LOG2E, ib1e = ib1p[0] * LOG2E;
    const float iw2 = iw2p[0], ib2 = ib2p[0];
    const float scale2 = 0.17677669529663687f * LOG2E;  // log2e/sqrt(32)
    const float cadd = ib1e - 16.0f * LOG2E;            // ib1*log2e - M2

    __shared__ unsigned short vt_lds[H_][D_][VTP];      // 36864B wave-private
    __shared__ unsigned short p_lds[H_][QT][PP];        // 36864B wave-private
    __shared__ unsigned short infl_lds[QT][IFP];        // 4352B  block-shared

    // Q fragments (2 q-subtiles), held all kernel
    bfx8 qf0 = *(const bfx8*)&q[((long)(b * N_ + q0 +      c)) * E_ + h * D_ + g * 8];
    bfx8 qf1 = *(const bfx8*)&q[((long)(b * N_ + q0 + 16 + c)) * E_ + h * D_ + g * 8];

    const unsigned short* kbase = &k[((long)(b * N_) + c) * E_ + h * D_ + g * 8];
    const int p2 = lane & 31, dh = (lane >> 5) * 16;
    const unsigned short* vbase = &v[((long)(b * N_) + 2 * p2) * E_ + h * D_ + dh];
    unsigned int* vtw = (unsigned int*)&vt_lds[h][0][0];

    // cooperative infl staging coords: 512 thr = 32 rows x 16 float4
    const int irow = tid >> 4, icol = (tid & 15) * 4;
    const float* ibase = &infl[((long)(b * N_ + q0 + irow)) * N_ + icol];

    fx4 o00 = {0,0,0,0}, o01 = {0,0,0,0}, o10 = {0,0,0,0}, o11 = {0,0,0,0};
    float l0 = 0.f, l1 = 0.f;
    const fx4 zero = {0,0,0,0};
    fx4 st[2][4];   // [qs][kt], all indices compile-time below

    // ---------------- prologue: chunk 0 ----------------
    float4 fcur = *(const float4*)&ibase[0];     // infl(0)
    float4 f4A  = *(const float4*)&ibase[KC];    // infl(1)
    bfx8 nk0 = *(const bfx8*)(kbase +  0L * E_);
    bfx8 nk1 = *(const bfx8*)(kbase + 16L * E_);
    bfx8 nk2 = *(const bfx8*)(kbase + 32L * E_);
    bfx8 nk3 = *(const bfx8*)(kbase + 48L * E_);
    bfx8 nva0 = *(const bfx8*)(vbase);
    bfx8 nva1 = *(const bfx8*)(vbase + 8);
    bfx8 nvb0 = *(const bfx8*)(vbase + E_);
    bfx8 nvb1 = *(const bfx8*)(vbase + E_ + 8);
    {   // write infl(0) to LDS (bf16)
        unsigned int w0 = (unsigned int)f2bf(fcur.x) | ((unsigned int)f2bf(fcur.y) << 16);
        unsigned int w1 = (unsigned int)f2bf(fcur.z) | ((unsigned int)f2bf(fcur.w) << 16);
        *(uint2*)&infl_lds[irow][icol] = make_uint2(w0, w1);
    }
    __syncthreads();
    // QK(0)
    __builtin_amdgcn_s_setprio(1);
    st[0][0] = __builtin_amdgcn_mfma_f32_16x16x32_bf16(nk0, qf0, zero, 0, 0, 0);
    st[1][0] = __builtin_amdgcn_mfma_f32_16x16x32_bf16(nk0, qf1, zero, 0, 0, 0);
    st[0][1] = __builtin_amdgcn_mfma_f32_16x16x32_bf16(nk1, qf0, zero, 0, 0, 0);
    st[1][1] = __builtin_amdgcn_mfma_f32_16x16x32_bf16(nk1, qf1, zero, 0, 0, 0);
    st[0][2] = __builtin_amdgcn_mfma_f32_16x16x32_bf16(nk2, qf0, zero, 0, 0, 0);
    st[1][2] = __builtin_amdgcn_mfma_f32_16x16x32_bf16(nk2, qf1, zero, 0, 0, 0);
    st[0][3] = __builtin_amdgcn_mfma_f32_16x16x32_bf16(nk3, qf0, zero, 0, 0, 0);
    st[1][3] = __builtin_amdgcn_mfma_f32_16x16x32_bf16(nk3, qf1, zero, 0, 0, 0);
    __builtin_amdgcn_s_setprio(0);
    {   // V-pack(0)
#pragma unroll
        for (int i = 0; i < 8; i++) {
            unsigned int val = (unsigned int)(unsigned short)nva0[i] |
                               ((unsigned int)(unsigned short)nvb0[i] << 16);
            vtw[(dh + i) * (VTP / 2) + p2] = val;
        }
#pragma unroll
        for (int i = 0; i < 8; i++) {
            unsigned int val = (unsigned int)(unsigned short)nva1[i] |
                               ((unsigned int)(unsigned short)nvb1[i] << 16);
            vtw[(dh + 8 + i) * (VTP / 2) + p2] = val;
        }
    }

    // ---------------- main loop ----------------
    for (int kk = 0; kk < N_; kk += KC) {
        const int kn  = (kk +     KC) & (N_ - 1);
        const int kn2 = (kk + 2 * KC) & (N_ - 1);

        // issue next-chunk loads (pinned above the barriers below)
        float4 f4N = *(const float4*)&ibase[kn2];
        nk0 = *(const bfx8*)(kbase + (long)(kn +  0) * E_);
        nk1 = *(const bfx8*)(kbase + (long)(kn + 16) * E_);
        nk2 = *(const bfx8*)(kbase + (long)(kn + 32) * E_);
        nk3 = *(const bfx8*)(kbase + (long)(kn + 48) * E_);
        const unsigned short* nvs = vbase + (long)kn * E_;
        nva0 = *(const bfx8*)(nvs);
        nva1 = *(const bfx8*)(nvs + 8);
        nvb0 = *(const bfx8*)(nvs + E_);
        nvb1 = *(const bfx8*)(nvs + E_ + 8);

        // softmax(kk): st + infl_lds -> pr -> p_lds   (all operands ready)
#pragma unroll
        for (int qs = 0; qs < 2; qs++) {
#pragma unroll
            for (int t = 0; t < 4; t++) {
                uint2 iw = *(const uint2*)&infl_lds[qs * 16 + c][t * 16 + g4];
                float fr[4];
                fr[0] = __uint_as_float(iw.x << 16);
                fr[1] = __uint_as_float(iw.x & 0xffff0000u);
                fr[2] = __uint_as_float(iw.y << 16);
                fr[3] = __uint_as_float(iw.y & 0xffff0000u);
                float pr[4];
#pragma unroll
                for (int r = 0; r < 4; r++) {
                    float s = fmaf(st[qs][t][r], scale2, fmaf(fr[r], iw1e, cadd));
                    float p = __builtin_amdgcn_exp2f(s);
                    if (qs == 0) l0 += p; else l1 += p;
                    pr[r] = p * fmaf(iw2, fr[r], ib2);
                }
                unsigned int lo = (unsigned int)f2bf(pr[0]) | ((unsigned int)f2bf(pr[1]) << 16);
                unsigned int hi = (unsigned int)f2bf(pr[2]) | ((unsigned int)f2bf(pr[3]) << 16);
                *(uint2*)&p_lds[h][qs * 16 + c][t * 16 + g4] = make_uint2(lo, hi);
            }
        }

        // PV(kk): p_lds + vt_lds -> acc
        __builtin_amdgcn_s_setprio(1);
#pragma unroll
        for (int kh = 0; kh < 2; kh++) {
            bfx8 vf0 = *(const bfx8*)&vt_lds[h][c][g * 8 + kh * 32];
            bfx8 vf1 = *(const bfx8*)&vt_lds[h][16 + c][g * 8 + kh * 32];
            bfx8 pf0 = *(const bfx8*)&p_lds[h][c][g * 8 + kh * 32];
            bfx8 pf1 = *(const bfx8*)&p_lds[h][16 + c][g * 8 + kh * 32];
            o00 = __builtin_amdgcn_mfma_f32_16x16x32_bf16(pf0, vf0, o00, 0, 0, 0);
            o01 = __builtin_amdgcn_mfma_f32_16x16x32_bf16(pf0, vf1, o01, 0, 0, 0);
            o10 = __builtin_amdgcn_mfma_f32_16x16x32_bf16(pf1, vf0, o10, 0, 0, 0);
            o11 = __builtin_amdgcn_mfma_f32_16x16x32_bf16(pf1, vf1, o11, 0, 0, 0);
        }
        __builtin_amdgcn_s_setprio(0);

        __syncthreads();   // (1) all waves done reading infl(kk)
        {   // write infl(kk+1) from regs loaded LAST body (no vmcnt wait)
            unsigned int w0 = (unsigned int)f2bf(f4A.x) | ((unsigned int)f2bf(f4A.y) << 16);
            unsigned int w1 = (unsigned int)f2bf(f4A.z) | ((unsigned int)f2bf(f4A.w) << 16);
            *(uint2*)&infl_lds[irow][icol] = make_uint2(w0, w1);
        }
        __syncthreads();   // (2) infl(kk+1) visible; prefetches pinned above

        if (kk != N_ - KC) {
            // QK(kk+1): K issued ~a full body ago
            __builtin_amdgcn_s_setprio(1);
            st[0][0] = __builtin_amdgcn_mfma_f32_16x16x32_bf16(nk0, qf0, zero, 0, 0, 0);
            st[1][0] = __builtin_amdgcn_mfma_f32_16x16x32_bf16(nk0, qf1, zero, 0, 0, 0);
            st[0][1] = __builtin_amdgcn_mfma_f32_16x16x32_bf16(nk1, qf0, zero, 0, 0, 0);
            st[1][1] = __builtin_amdgcn_mfma_f32_16x16x32_bf16(nk1, qf1, zero, 0, 0, 0);
            st[0][2] = __builtin_amdgcn_mfma_f32_16x16x32_bf16(nk2, qf0, zero, 0, 0, 0);
            st[1][2] = __builtin_amdgcn_mfma_f32_16x16x32_bf16(nk2, qf1, zero, 0, 0, 0);
            st[0][3] = __builtin_amdgcn_mfma_f32_16x16x32_bf16(nk3, qf0, zero, 0, 0, 0);
            st[1][3] = __builtin_amdgcn_mfma_f32_16x16x32_bf16(nk3, qf1, zero, 0, 0, 0);
            __builtin_amdgcn_s_setprio(0);
            // V-pack(kk+1) (PV(kk) already consumed vt; wave-private)
#pragma unroll
            for (int i = 0; i < 8; i++) {
                unsigned int val = (unsigned int)(unsigned short)nva0[i] |
                                   ((unsigned int)(unsigned short)nvb0[i] << 16);
                vtw[(dh + i) * (VTP / 2) + p2] = val;
            }
#pragma unroll
            for (int i = 0; i < 8; i++) {
                unsigned int val = (unsigned int)(unsigned short)nva1[i] |
                                   ((unsigned int)(unsigned short)nvb1[i] << 16);
                vtw[(dh + 8 + i) * (VTP / 2) + p2] = val;
            }
        }
        f4A = f4N;
    }

    // ---------------- epilogue ----------------
    float l0r = l0;
    l0r += __shfl_xor(l0r, 16); l0r += __shfl_xor(l0r, 32);
    float l1r = l1;
    l1r += __shfl_xor(l1r, 16); l1r += __shfl_xor(l1r, 32);
#pragma unroll
    for (int r = 0; r < 4; r++) {
        int src = (lane & 48) | (g4 + r);
        float inv0 = 1.0f / __shfl(l0r, src, 64);
        float inv1 = 1.0f / __shfl(l1r, src, 64);
        long row0 = ((long)(b * N_ + q0 +      g4 + r)) * E_ + h * D_;
        long row1 = ((long)(b * N_ + q0 + 16 + g4 + r)) * E_ + h * D_;
        out[row0 + c]      = f2bf(o00[r] * inv0);
        out[row0 + 16 + c] = f2bf(o01[r] * inv0);
        out[row1 + c]      = f2bf(o10[r] * inv1);
        out[row1 + 16 + c] = f2bf(o11[r] * inv1);
    }
}

// ------------------------------- launch ---------------------------------------
extern "C" void kernel_launch(void* const* d_in, const int* in_sizes, int n_in,
                              void* d_out, int out_size, void* d_ws, size_t ws_size,
                              hipStream_t stream)
{
    (void)in_sizes; (void)n_in; (void)out_size; (void)ws_size;
    const float* x    = (const float*)d_in[0];
    const float* infl = (const float*)d_in[1];
    const float* Wq   = (const float*)d_in[2];
    const float* Wk   = (const float*)d_in[3];
    const float* Wv   = (const float*)d_in[4];
    const float* Wo   = (const float*)d_in[5];
    const float* bo   = (const float*)d_in[6];
    const float* iw1  = (const float*)d_in[7];
    const float* ib1  = (const float*)d_in[8];
    const float* iw2  = (const float*)d_in[9];
    const float* ib2  = (const float*)d_in[10];
    const float* W1   = (const float*)d_in[11];
    const float* b1   = (const float*)d_in[12];
    const float* W2   = (const float*)d_in[13];
    const float* b2   = (const float*)d_in[14];
    const float* g1   = (const float*)d_in[15];
    const float* be1  = (const float*)d_in[16];
    const float* g2   = (const float*)d_in[17];
    const float* be2  = (const float*)d_in[18];

    char* base = (char*)d_ws;
    float*          hb  = (float*)base;                                   // 8 MB
    unsigned short* lnb = (unsigned short*)(base + (8  << 20));           // 4 MB
    unsigned short* qb  = (unsigned short*)(base + (12 << 20));           // 4 MB
    unsigned short* kb  = (unsigned short*)(base + (16 << 20));           // 4 MB
    unsigned short* vb  = (unsigned short*)(base + (20 << 20));           // 4 MB
    unsigned short* wqt = (unsigned short*)(base + (24 << 20));           // 6x128KB
    unsigned short* wkt = wqt + 65536;
    unsigned short* wvt = wkt + 65536;
    unsigned short* wot = wvt + 65536;
    unsigned short* w1t = wot + 65536;
    unsigned short* w2t = w1t + 65536;

    dim3 gemm_grid(128, 4);

    prep_w<<<dim3(8, 8, 6), 256, 0, stream>>>(Wq, Wk, Wv, Wo, W1, W2,
                                              wqt, wkt, wvt, wot, w1t, w2t);
    // 1. ln1 = LN(x) -> bf16
    ln_kernel<<<B_ * N_, 256, 0, stream>>>(x, g1, be1, lnb);
    // 2. q,k,v in ONE launch (z selects weight/output)
    gemm_qkv<<<dim3(128, 4, 3), 256, 0, stream>>>(lnb, wqt, qb, wkt, kb, wvt, vb);
    // 3. attention (bf16 out into lnb)
    attn_mfma<<<B_ * (N_ / QT), 512, 0, stream>>>(qb, kb, vb, infl,
                                                  iw1, ib1, iw2, ib2, lnb);
    // 4. h = attn @ Wo + bo + x (fp32)
    gemm_mfma<<<gemm_grid, 256, 0, stream>>>(lnb, wot, bo, x, hb, 0, 0);
    // 5. ln2 = LN(h) -> bf16
    ln_kernel<<<B_ * N_, 256, 0, stream>>>(hb, g2, be2, lnb);
    // 6. t = relu(ln2 @ W1 + b1) -> bf16 (reuse qb)
    gemm_mfma<<<gemm_grid, 256, 0, stream>>>(lnb, w1t, b1, nullptr, qb, 1, 1);
    // 7. out = t @ W2 + b2 + h (fp32)
    gemm_mfma<<<gemm_grid, 256, 0, stream>>>(qb, w2t, b2, hb, (float*)d_out, 0, 0);
}

// Round 9
// 149.068 us; speedup vs baseline: 1.7609x; 1.3315x over previous
//
#include <hip/hip_runtime.h>
#include <hip/hip_bf16.h>

#define B_  4
#define N_  2048
#define E_  256
#define H_  8
#define D_  32
#define QT  32   // q-rows per block
#define KC  64   // keys per chunk
#define HPB 4    // heads per block
#define VTP 72   // V^T row stride (ushorts): 144B, 16B-aligned
#define PP  72   // P row stride (ushorts)
#define IFP 68   // infl row stride (ushorts): 136B, 8B-aligned
#define LOG2E 1.4426950408889634f

typedef __attribute__((ext_vector_type(8))) short bfx8;
typedef __attribute__((ext_vector_type(4))) float fx4;

__device__ __forceinline__ unsigned short f2bf(float f) {
    unsigned int u = __float_as_uint(f);
    u += 0x7fffu + ((u >> 16) & 1u);   // round-to-nearest-even
    return (unsigned short)(u >> 16);
}

// ---------- prep: Wt[n][k] = bf16(W[k][n]) for 6 weight matrices ----------
__global__ __launch_bounds__(256) void prep_w(
    const float* Wa, const float* Wb, const float* Wc,
    const float* Wd, const float* We, const float* Wf,
    unsigned short* Oa, unsigned short* Ob, unsigned short* Oc,
    unsigned short* Od, unsigned short* Oe, unsigned short* Of)
{
    int z = blockIdx.z;
    const float* src = z == 0 ? Wa : z == 1 ? Wb : z == 2 ? Wc
                     : z == 3 ? Wd : z == 4 ? We : Wf;
    unsigned short* dst = z == 0 ? Oa : z == 1 ? Ob : z == 2 ? Oc
                        : z == 3 ? Od : z == 4 ? Oe : Of;
    __shared__ float t[32][33];
    int n0 = blockIdx.x * 32, k0 = blockIdx.y * 32;
    int tx = threadIdx.x & 31, ty = threadIdx.x >> 5;
#pragma unroll
    for (int i = 0; i < 4; i++)
        t[ty + i * 8][tx] = src[(k0 + ty + i * 8) * E_ + n0 + tx];
    __syncthreads();
#pragma unroll
    for (int i = 0; i < 4; i++)
        dst[(n0 + ty + i * 8) * E_ + k0 + tx] = f2bf(t[tx][ty + i * 8]);
}

// ---------- LayerNorm: one block (256 thr) per row; bf16 out ----------
__global__ __launch_bounds__(256) void ln_kernel(const float* __restrict__ x,
                                                 const float* __restrict__ g,
                                                 const float* __restrict__ be,
                                                 unsigned short* __restrict__ out)
{
    long row = blockIdx.x;
    int t = threadIdx.x;
    float v = x[row * E_ + t];
    float s = v, s2 = v * v;
#pragma unroll
    for (int off = 32; off; off >>= 1) {
        s  += __shfl_xor(s,  off, 64);
        s2 += __shfl_xor(s2, off, 64);
    }
    __shared__ float rs[4], rs2[4];
    int w = t >> 6;
    if ((t & 63) == 0) { rs[w] = s; rs2[w] = s2; }
    __syncthreads();
    s  = rs[0] + rs[1] + rs[2] + rs[3];
    s2 = rs2[0] + rs2[1] + rs2[2] + rs2[3];
    float mu  = s * (1.0f / E_);
    float var = s2 * (1.0f / E_) - mu * mu;
    float rstd = rsqrtf(var + 1e-5f);
    out[row * E_ + t] = f2bf((v - mu) * rstd * g[t] + be[t]);
}

// ---------- bf16 MFMA GEMM core (64x64 tile, K=256 strip in LDS) ----------
__device__ __forceinline__ void gemm_core(
    const unsigned short* __restrict__ A,
    const unsigned short* __restrict__ Wt,
    const float* __restrict__ bias,
    const float* __restrict__ resid,
    void* __restrict__ Cv, int relu, int obf, int m0, int n0)
{
    __shared__ unsigned short As[64 * 264];
    __shared__ unsigned short Bs[64 * 264];
    int tid = threadIdx.x;

    {   // stage both 64x256 strips (contiguous rows), coalesced 16B/lane
        const unsigned short* Ab = A  + (long)m0 * E_;
        const unsigned short* Bb = Wt + (long)n0 * E_;
        bfx8 va[8], vb[8];
#pragma unroll
        for (int i = 0; i < 8; i++) va[i] = *(const bfx8*)&Ab[(i * 256 + tid) * 8];
#pragma unroll
        for (int i = 0; i < 8; i++) vb[i] = *(const bfx8*)&Bb[(i * 256 + tid) * 8];
#pragma unroll
        for (int i = 0; i < 8; i++) {
            int fo = i * 256 + tid;
            int row = fo >> 5, c8 = fo & 31;
            *(bfx8*)&As[row * 264 + c8 * 8] = va[i];
            *(bfx8*)&Bs[row * 264 + c8 * 8] = vb[i];
        }
    }
    __syncthreads();

    int lane = tid & 63, w = tid >> 6;
    int c = lane & 15, g = lane >> 4;
    int wm = (w >> 1) * 32, wn = (w & 1) * 32;
    fx4 acc[2][2] = {};

#pragma unroll
    for (int ks = 0; ks < 8; ks++) {
        bfx8 a0 = *(const bfx8*)&As[(wm + c)      * 264 + ks * 32 + g * 8];
        bfx8 a1 = *(const bfx8*)&As[(wm + 16 + c) * 264 + ks * 32 + g * 8];
        bfx8 b0 = *(const bfx8*)&Bs[(wn + c)      * 264 + ks * 32 + g * 8];
        bfx8 b1 = *(const bfx8*)&Bs[(wn + 16 + c) * 264 + ks * 32 + g * 8];
        acc[0][0] = __builtin_amdgcn_mfma_f32_16x16x32_bf16(a0, b0, acc[0][0], 0, 0, 0);
        acc[0][1] = __builtin_amdgcn_mfma_f32_16x16x32_bf16(a0, b1, acc[0][1], 0, 0, 0);
        acc[1][0] = __builtin_amdgcn_mfma_f32_16x16x32_bf16(a1, b0, acc[1][0], 0, 0, 0);
        acc[1][1] = __builtin_amdgcn_mfma_f32_16x16x32_bf16(a1, b1, acc[1][1], 0, 0, 0);
    }

#pragma unroll
    for (int fm = 0; fm < 2; fm++)
#pragma unroll
        for (int r = 0; r < 4; r++) {
            int m = m0 + wm + fm * 16 + g * 4 + r;
#pragma unroll
            for (int fn = 0; fn < 2; fn++) {
                int n = n0 + wn + fn * 16 + c;
                float o = acc[fm][fn][r];
                if (bias)  o += bias[n];
                if (relu)  o = fmaxf(o, 0.f);
                if (resid) o += resid[(long)m * E_ + n];
                if (obf) ((unsigned short*)Cv)[(long)m * E_ + n] = f2bf(o);
                else     ((float*)Cv)[(long)m * E_ + n] = o;
            }
        }
}

__global__ __launch_bounds__(256, 2) void gemm_mfma(
    const unsigned short* __restrict__ A,
    const unsigned short* __restrict__ Wt,
    const float* __restrict__ bias,
    const float* __restrict__ resid,
    void* __restrict__ Cv, int relu, int obf)
{
    gemm_core(A, Wt, bias, resid, Cv, relu, obf, blockIdx.x * 64, blockIdx.y * 64);
}

// merged QKV: blockIdx.z selects weight/output
__global__ __launch_bounds__(256, 2) void gemm_qkv(
    const unsigned short* __restrict__ A,
    const unsigned short* __restrict__ Wq, unsigned short* __restrict__ qo,
    const unsigned short* __restrict__ Wk, unsigned short* __restrict__ ko,
    const unsigned short* __restrict__ Wv, unsigned short* __restrict__ vo)
{
    int z = blockIdx.z;
    const unsigned short* Wt = z == 0 ? Wq : z == 1 ? Wk : Wv;
    unsigned short*       Cv = z == 0 ? qo : z == 1 ? ko : vo;
    gemm_core(A, Wt, nullptr, nullptr, Cv, 0, 1, blockIdx.x * 64, blockIdx.y * 64);
}

// ---------- MFMA flash attention: 4 heads/block, dbuf infl, 1 barrier/body ----
// fixed-max softmax: p' = exp2(s*log2e - M2); out = (sum p'*rw*v)/(sum p').
// 2 blocks/CU = independent barrier domains; infl double-buffer: write buf[nxt]
// while softmax reads buf[cur]; single end-of-body barrier does both handoffs.
// xcd = bx&7 maps 1:1 to (batch, head-group): K/V/Q working set 1.5MB per L2.
__global__ __launch_bounds__(256, 2) void attn_mfma(
    const unsigned short* __restrict__ q,
    const unsigned short* __restrict__ k,
    const unsigned short* __restrict__ v,
    const float* __restrict__ infl,
    const float* __restrict__ iw1p, const float* __restrict__ ib1p,
    const float* __restrict__ iw2p, const float* __restrict__ ib2p,
    unsigned short* __restrict__ out)
{
    const int bx  = blockIdx.x;                 // 512 blocks
    const int xcd = bx & 7;
    const int b   = xcd >> 1;                   // batch
    const int hg  = (xcd & 1) * HPB;            // head-group base
    const int q0  = (bx >> 3) * QT;
    const int tid = threadIdx.x;
    const int h    = tid >> 6;                  // wave id 0..3
    const int head = hg + h;
    const int lane = tid & 63;
    const int c = lane & 15, g = lane >> 4, g4 = g * 4;

    const float iw1e = iw1p[0] * LOG2E, ib1e = ib1p[0] * LOG2E;
    const float iw2 = iw2p[0], ib2 = ib2p[0];
    const float scale2 = 0.17677669529663687f * LOG2E;  // log2e/sqrt(32)
    const float cadd = ib1e - 16.0f * LOG2E;            // ib1*log2e - M2

    __shared__ unsigned short vt_lds[HPB][D_][VTP];     // 18432B wave-private
    __shared__ unsigned short p_lds[HPB][QT][PP];       // 18432B wave-private
    __shared__ unsigned short infl_lds[2][QT][IFP];     // 8704B  block-shared dbuf

    // Q fragments (2 q-subtiles), held all kernel
    bfx8 qf0 = *(const bfx8*)&q[((long)(b * N_ + q0 +      c)) * E_ + head * D_ + g * 8];
    bfx8 qf1 = *(const bfx8*)&q[((long)(b * N_ + q0 + 16 + c)) * E_ + head * D_ + g * 8];

    const unsigned short* kbase = &k[((long)(b * N_) + c) * E_ + head * D_ + g * 8];
    const int p2 = lane & 31, dh = (lane >> 5) * 16;
    const unsigned short* vbase = &v[((long)(b * N_) + 2 * p2) * E_ + head * D_ + dh];
    unsigned int* vtw = (unsigned int*)&vt_lds[h][0][0];

    // cooperative infl staging: 256 thr = 32 rows x 8 thr; 2 float4 each
    const int irow = tid >> 3, icol = (tid & 7) * 8;
    const float* ibase = &infl[((long)(b * N_ + q0 + irow)) * N_ + icol];

    fx4 o00 = {0,0,0,0}, o01 = {0,0,0,0}, o10 = {0,0,0,0}, o11 = {0,0,0,0};
    float l0 = 0.f, l1 = 0.f;
    const fx4 zero = {0,0,0,0};
    fx4 st[2][4];   // [qs][kt], compile-time indices only

    // ---------------- prologue: chunk 0 ----------------
    float4 i00 = *(const float4*)&ibase[0];
    float4 i01 = *(const float4*)&ibase[4];
    float4 fA0 = *(const float4*)&ibase[KC];
    float4 fA1 = *(const float4*)&ibase[KC + 4];
    bfx8 nk0 = *(const bfx8*)(kbase +  0L * E_);
    bfx8 nk1 = *(const bfx8*)(kbase + 16L * E_);
    bfx8 nk2 = *(const bfx8*)(kbase + 32L * E_);
    bfx8 nk3 = *(const bfx8*)(kbase + 48L * E_);
    bfx8 nva0 = *(const bfx8*)(vbase);
    bfx8 nva1 = *(const bfx8*)(vbase + 8);
    bfx8 nvb0 = *(const bfx8*)(vbase + E_);
    bfx8 nvb1 = *(const bfx8*)(vbase + E_ + 8);
    {   // write infl(0) to buf0 (bf16)
        unsigned int w0 = (unsigned int)f2bf(i00.x) | ((unsigned int)f2bf(i00.y) << 16);
        unsigned int w1 = (unsigned int)f2bf(i00.z) | ((unsigned int)f2bf(i00.w) << 16);
        unsigned int w2 = (unsigned int)f2bf(i01.x) | ((unsigned int)f2bf(i01.y) << 16);
        unsigned int w3 = (unsigned int)f2bf(i01.z) | ((unsigned int)f2bf(i01.w) << 16);
        *(uint2*)&infl_lds[0][irow][icol]     = make_uint2(w0, w1);
        *(uint2*)&infl_lds[0][irow][icol + 4] = make_uint2(w2, w3);
    }
    __syncthreads();
    // QK(0)
    __builtin_amdgcn_s_setprio(1);
    st[0][0] = __builtin_amdgcn_mfma_f32_16x16x32_bf16(nk0, qf0, zero, 0, 0, 0);
    st[1][0] = __builtin_amdgcn_mfma_f32_16x16x32_bf16(nk0, qf1, zero, 0, 0, 0);
    st[0][1] = __builtin_amdgcn_mfma_f32_16x16x32_bf16(nk1, qf0, zero, 0, 0, 0);
    st[1][1] = __builtin_amdgcn_mfma_f32_16x16x32_bf16(nk1, qf1, zero, 0, 0, 0);
    st[0][2] = __builtin_amdgcn_mfma_f32_16x16x32_bf16(nk2, qf0, zero, 0, 0, 0);
    st[1][2] = __builtin_amdgcn_mfma_f32_16x16x32_bf16(nk2, qf1, zero, 0, 0, 0);
    st[0][3] = __builtin_amdgcn_mfma_f32_16x16x32_bf16(nk3, qf0, zero, 0, 0, 0);
    st[1][3] = __builtin_amdgcn_mfma_f32_16x16x32_bf16(nk3, qf1, zero, 0, 0, 0);
    __builtin_amdgcn_s_setprio(0);
    {   // V-pack(0)
#pragma unroll
        for (int i = 0; i < 8; i++) {
            unsigned int val = (unsigned int)(unsigned short)nva0[i] |
                               ((unsigned int)(unsigned short)nvb0[i] << 16);
            vtw[(dh + i) * (VTP / 2) + p2] = val;
        }
#pragma unroll
        for (int i = 0; i < 8; i++) {
            unsigned int val = (unsigned int)(unsigned short)nva1[i] |
                               ((unsigned int)(unsigned short)nvb1[i] << 16);
            vtw[(dh + 8 + i) * (VTP / 2) + p2] = val;
        }
    }

    // ---------------- main loop ----------------
    for (int kk = 0; kk < N_; kk += KC) {
        const int cur = (kk >> 6) & 1, nxt = cur ^ 1;
        const int kn  = (kk +     KC) & (N_ - 1);
        const int kn2 = (kk + 2 * KC) & (N_ - 1);

        // issue next-chunk loads (V first, K, then infl 2 ahead)
        const unsigned short* nvs = vbase + (long)kn * E_;
        nva0 = *(const bfx8*)(nvs);
        nva1 = *(const bfx8*)(nvs + 8);
        nvb0 = *(const bfx8*)(nvs + E_);
        nvb1 = *(const bfx8*)(nvs + E_ + 8);
        nk0 = *(const bfx8*)(kbase + (long)(kn +  0) * E_);
        nk1 = *(const bfx8*)(kbase + (long)(kn + 16) * E_);
        nk2 = *(const bfx8*)(kbase + (long)(kn + 32) * E_);
        nk3 = *(const bfx8*)(kbase + (long)(kn + 48) * E_);
        float4 fN0 = *(const float4*)&ibase[kn2];
        float4 fN1 = *(const float4*)&ibase[kn2 + 4];

        // write infl(kk+1) into buf[nxt] from regs loaded LAST body (no wait;
        // readers of buf[nxt] finished at the previous body's barrier)
        {
            unsigned int w0 = (unsigned int)f2bf(fA0.x) | ((unsigned int)f2bf(fA0.y) << 16);
            unsigned int w1 = (unsigned int)f2bf(fA0.z) | ((unsigned int)f2bf(fA0.w) << 16);
            unsigned int w2 = (unsigned int)f2bf(fA1.x) | ((unsigned int)f2bf(fA1.y) << 16);
            unsigned int w3 = (unsigned int)f2bf(fA1.z) | ((unsigned int)f2bf(fA1.w) << 16);
            *(uint2*)&infl_lds[nxt][irow][icol]     = make_uint2(w0, w1);
            *(uint2*)&infl_lds[nxt][irow][icol + 4] = make_uint2(w2, w3);
        }

        // softmax(kk): st + infl_lds[cur] -> pr -> p_lds
#pragma unroll
        for (int qs = 0; qs < 2; qs++) {
#pragma unroll
            for (int t = 0; t < 4; t++) {
                uint2 iw = *(const uint2*)&infl_lds[cur][qs * 16 + c][t * 16 + g4];
                float fr[4];
                fr[0] = __uint_as_float(iw.x << 16);
                fr[1] = __uint_as_float(iw.x & 0xffff0000u);
                fr[2] = __uint_as_float(iw.y << 16);
                fr[3] = __uint_as_float(iw.y & 0xffff0000u);
                float pr[4];
#pragma unroll
                for (int r = 0; r < 4; r++) {
                    float s = fmaf(st[qs][t][r], scale2, fmaf(fr[r], iw1e, cadd));
                    float p = __builtin_amdgcn_exp2f(s);
                    if (qs == 0) l0 += p; else l1 += p;
                    pr[r] = p * fmaf(iw2, fr[r], ib2);
                }
                unsigned int lo = (unsigned int)f2bf(pr[0]) | ((unsigned int)f2bf(pr[1]) << 16);
                unsigned int hi = (unsigned int)f2bf(pr[2]) | ((unsigned int)f2bf(pr[3]) << 16);
                *(uint2*)&p_lds[h][qs * 16 + c][t * 16 + g4] = make_uint2(lo, hi);
            }
        }

        // PV(kk)
        __builtin_amdgcn_s_setprio(1);
#pragma unroll
        for (int kh = 0; kh < 2; kh++) {
            bfx8 vf0 = *(const bfx8*)&vt_lds[h][c][g * 8 + kh * 32];
            bfx8 vf1 = *(const bfx8*)&vt_lds[h][16 + c][g * 8 + kh * 32];
            bfx8 pf0 = *(const bfx8*)&p_lds[h][c][g * 8 + kh * 32];
            bfx8 pf1 = *(const bfx8*)&p_lds[h][16 + c][g * 8 + kh * 32];
            o00 = __builtin_amdgcn_mfma_f32_16x16x32_bf16(pf0, vf0, o00, 0, 0, 0);
            o01 = __builtin_amdgcn_mfma_f32_16x16x32_bf16(pf0, vf1, o01, 0, 0, 0);
            o10 = __builtin_amdgcn_mfma_f32_16x16x32_bf16(pf1, vf0, o10, 0, 0, 0);
            o11 = __builtin_amdgcn_mfma_f32_16x16x32_bf16(pf1, vf1, o11, 0, 0, 0);
        }
        __builtin_amdgcn_s_setprio(0);

        __syncthreads();   // buf[cur] reads done; buf[nxt] writes visible

        if (kk != N_ - KC) {
            // QK(kk+1): K issued one body ago
            __builtin_amdgcn_s_setprio(1);
            st[0][0] = __builtin_amdgcn_mfma_f32_16x16x32_bf16(nk0, qf0, zero, 0, 0, 0);
            st[1][0] = __builtin_amdgcn_mfma_f32_16x16x32_bf16(nk0, qf1, zero, 0, 0, 0);
            st[0][1] = __builtin_amdgcn_mfma_f32_16x16x32_bf16(nk1, qf0, zero, 0, 0, 0);
            st[1][1] = __builtin_amdgcn_mfma_f32_16x16x32_bf16(nk1, qf1, zero, 0, 0, 0);
            st[0][2] = __builtin_amdgcn_mfma_f32_16x16x32_bf16(nk2, qf0, zero, 0, 0, 0);
            st[1][2] = __builtin_amdgcn_mfma_f32_16x16x32_bf16(nk2, qf1, zero, 0, 0, 0);
            st[0][3] = __builtin_amdgcn_mfma_f32_16x16x32_bf16(nk3, qf0, zero, 0, 0, 0);
            st[1][3] = __builtin_amdgcn_mfma_f32_16x16x32_bf16(nk3, qf1, zero, 0, 0, 0);
            __builtin_amdgcn_s_setprio(0);
            // V-pack(kk+1)
#pragma unroll
            for (int i = 0; i < 8; i++) {
                unsigned int val = (unsigned int)(unsigned short)nva0[i] |
                                   ((unsigned int)(unsigned short)nvb0[i] << 16);
                vtw[(dh + i) * (VTP / 2) + p2] = val;
            }
#pragma unroll
            for (int i = 0; i < 8; i++) {
                unsigned int val = (unsigned int)(unsigned short)nva1[i] |
                                   ((unsigned int)(unsigned short)nvb1[i] << 16);
                vtw[(dh + 8 + i) * (VTP / 2) + p2] = val;
            }
        }
        fA0 = fN0; fA1 = fN1;
    }

    // ---------------- epilogue ----------------
    float l0r = l0;
    l0r += __shfl_xor(l0r, 16); l0r += __shfl_xor(l0r, 32);
    float l1r = l1;
    l1r += __shfl_xor(l1r, 16); l1r += __shfl_xor(l1r, 32);
#pragma unroll
    for (int r = 0; r < 4; r++) {
        int src = (lane & 48) | (g4 + r);
        float inv0 = 1.0f / __shfl(l0r, src, 64);
        float inv1 = 1.0f / __shfl(l1r, src, 64);
        long row0 = ((long)(b * N_ + q0 +      g4 + r)) * E_ + head * D_;
        long row1 = ((long)(b * N_ + q0 + 16 + g4 + r)) * E_ + head * D_;
        out[row0 + c]      = f2bf(o00[r] * inv0);
        out[row0 + 16 + c] = f2bf(o01[r] * inv0);
        out[row1 + c]      = f2bf(o10[r] * inv1);
        out[row1 + 16 + c] = f2bf(o11[r] * inv1);
    }
}

// ------------------------------- launch ---------------------------------------
extern "C" void kernel_launch(void* const* d_in, const int* in_sizes, int n_in,
                              void* d_out, int out_size, void* d_ws, size_t ws_size,
                              hipStream_t stream)
{
    (void)in_sizes; (void)n_in; (void)out_size; (void)ws_size;
    const float* x    = (const float*)d_in[0];
    const float* infl = (const float*)d_in[1];
    const float* Wq   = (const float*)d_in[2];
    const float* Wk   = (const float*)d_in[3];
    const float* Wv   = (const float*)d_in[4];
    const float* Wo   = (const float*)d_in[5];
    const float* bo   = (const float*)d_in[6];
    const float* iw1  = (const float*)d_in[7];
    const float* ib1  = (const float*)d_in[8];
    const float* iw2  = (const float*)d_in[9];
    const float* ib2  = (const float*)d_in[10];
    const float* W1   = (const float*)d_in[11];
    const float* b1   = (const float*)d_in[12];
    const float* W2   = (const float*)d_in[13];
    const float* b2   = (const float*)d_in[14];
    const float* g1   = (const float*)d_in[15];
    const float* be1  = (const float*)d_in[16];
    const float* g2   = (const float*)d_in[17];
    const float* be2  = (const float*)d_in[18];

    char* base = (char*)d_ws;
    float*          hb  = (float*)base;                                   // 8 MB
    unsigned short* lnb = (unsigned short*)(base + (8  << 20));           // 4 MB
    unsigned short* qb  = (unsigned short*)(base + (12 << 20));           // 4 MB
    unsigned short* kb  = (unsigned short*)(base + (16 << 20));           // 4 MB
    unsigned short* vb  = (unsigned short*)(base + (20 << 20));           // 4 MB
    unsigned short* wqt = (unsigned short*)(base + (24 << 20));           // 6x128KB
    unsigned short* wkt = wqt + 65536;
    unsigned short* wvt = wkt + 65536;
    unsigned short* wot = wvt + 65536;
    unsigned short* w1t = wot + 65536;
    unsigned short* w2t = w1t + 65536;

    dim3 gemm_grid(128, 4);

    prep_w<<<dim3(8, 8, 6), 256, 0, stream>>>(Wq, Wk, Wv, Wo, W1, W2,
                                              wqt, wkt, wvt, wot, w1t, w2t);
    // 1. ln1 = LN(x) -> bf16
    ln_kernel<<<B_ * N_, 256, 0, stream>>>(x, g1, be1, lnb);
    // 2. q,k,v in ONE launch (z selects weight/output)
    gemm_qkv<<<dim3(128, 4, 3), 256, 0, stream>>>(lnb, wqt, qb, wkt, kb, wvt, vb);
    // 3. attention (bf16 out into lnb); 512 blocks, 2/CU
    attn_mfma<<<B_ * (N_ / QT) * 2, 256, 0, stream>>>(qb, kb, vb, infl,
                                                      iw1, ib1, iw2, ib2, lnb);
    // 4. h = attn @ Wo + bo + x (fp32)
    gemm_mfma<<<gemm_grid, 256, 0, stream>>>(lnb, wot, bo, x, hb, 0, 0);
    // 5. ln2 = LN(h) -> bf16
    ln_kernel<<<B_ * N_, 256, 0, stream>>>(hb, g2, be2, lnb);
    // 6. t = relu(ln2 @ W1 + b1) -> bf16 (reuse qb)
    gemm_mfma<<<gemm_grid, 256, 0, stream>>>(lnb, w1t, b1, nullptr, qb, 1, 1);
    // 7. out = t @ W2 + b2 + h (fp32)
    gemm_mfma<<<gemm_grid, 256, 0, stream>>>(qb, w2t, b2, hb, (float*)d_out, 0, 0);
}